// Round 13
// baseline (201.285 us; speedup 1.0000x reference)
//
#include <hip/hip_runtime.h>
#include <cstdint>
#include <cstddef>

#define NB 512
#define NL 32
#define KD 512     // P*D
#define KSLAB 256  // k-range per cost block
#define PASS 128   // k per staging pass

// swizzled float-offset of chunk ch (4 floats) of row `row` in a [32][128] pass buffer.
__device__ __forceinline__ int swz128(int row, int ch) {
  int csw = (ch & ~15) | ((ch ^ (row >> 1)) & 15);
  return row * PASS + csw * 4;
}

__device__ __forceinline__ float readlane_f(float x, int lane) {
  return __int_as_float(__builtin_amdgcn_readlane(__float_as_int(x), lane));
}
__device__ __forceinline__ int readlane_i(int x, int lane) {
  return __builtin_amdgcn_readlane(x, lane);
}

template<int CTRL, int RM>
__device__ __forceinline__ float dppmin(float x) {
  int m = __builtin_amdgcn_update_dpp(__float_as_int(x), __float_as_int(x), CTRL, RM, 0xf, false);
  return fminf(x, __int_as_float(m));
}
// min over lanes 0..31, broadcast to all lanes via SGPR
__device__ __forceinline__ float wave_min32_bcast(float x) {
  x = dppmin<0xB1, 0xf>(x);   // quad_perm xor1
  x = dppmin<0x4E, 0xf>(x);   // quad_perm xor2
  x = dppmin<0x124, 0xf>(x);  // row_ror:4
  x = dppmin<0x128, 0xf>(x);  // row_ror:8 -> row16 min everywhere
  x = dppmin<0x142, 0xa>(x);  // row_bcast:15 -> lanes 16..31 = min(lanes 0..31)
  return readlane_f(x, 31);
}

// Fused: 1024 blocks x 256 thr. Each block computes a half-K cost plane
// (R12-proven body, 32 KB LDS, launch_bounds (256,2) -> VGPR cap 128, no spill).
// Per-batch ticket: the SECOND of a batch's two blocks runs the hungarian tail
// on wave 0 (overlapped with other blocks' cost work); the 512th hung
// completion runs the finalize (R9-proven device-scope ticket pattern).
__global__ __launch_bounds__(256, 2)
void fused_kernel(const float* __restrict__ pred,
                  const float* __restrict__ prob,
                  const float* __restrict__ tgt,
                  const float* __restrict__ lmask,
                  const int* __restrict__ clf,
                  float* __restrict__ cost_part,
                  unsigned int* __restrict__ bticket,   // [NB], zeroed per call
                  unsigned int* __restrict__ gticket,   // [1], zeroed per call
                  float* __restrict__ part,
                  float* __restrict__ out) {
  __shared__ float smem[8192];   // 32 KB: predH/tgtH; later cs[1024] + winflag
  const int bid = blockIdx.x;
  const int b  = bid >> 1;
  const int ks = (bid & 1) * KSLAB;
  const int tid = threadIdx.x;
  float* predH = smem;
  float* tgtH  = smem + 4096;

  const int w = tid >> 6, l = tid & 63;   // 4 waves; wave w owns a 32-float k-slice/pass
  const int ti = l >> 3, tj = l & 7;      // 8x8 lanes of 4x4 output tiles
  float acc[4][4];
#pragma unroll
  for (int a = 0; a < 4; ++a)
#pragma unroll
    for (int c2 = 0; c2 < 4; ++c2) acc[a][c2] = 0.f;

  for (int hp = 0; hp < 2; ++hp) {
    __syncthreads();
    const size_t base = (size_t)b * (NL * KD) + ks + hp * PASS;
#pragma unroll
    for (int it = 0; it < 4; ++it) {
      int chunk = tid + it * 256;          // 0..1023 -> row, chunk-in-row
      int row = chunk >> 5, ch = chunk & 31;
      const float4 pv = *reinterpret_cast<const float4*>(pred + base + (size_t)row * KD + ch * 4);
      const float4 tv = *reinterpret_cast<const float4*>(tgt  + base + (size_t)row * KD + ch * 4);
      int off = swz128(row, ch);
      *reinterpret_cast<float4*>(predH + off) = pv;
      *reinterpret_cast<float4*>(tgtH  + off) = tv;
    }
    __syncthreads();
#pragma unroll
    for (int c0 = 0; c0 < 8; ++c0) {
      const int c = (w << 3) + c0;         // wave's 8 chunks of this pass
      float4 pr[4], tg[4];
#pragma unroll
      for (int r = 0; r < 4; ++r) {
        pr[r] = *reinterpret_cast<const float4*>(predH + swz128(4 * ti + r, c));
        tg[r] = *reinterpret_cast<const float4*>(tgtH  + swz128(4 * tj + r, c));
      }
#pragma unroll
      for (int a = 0; a < 4; ++a)
#pragma unroll
        for (int c2 = 0; c2 < 4; ++c2) {
          float d;
          d = pr[a].x - tg[c2].x; acc[a][c2] += d * d;
          d = pr[a].y - tg[c2].y; acc[a][c2] += d * d;
          d = pr[a].z - tg[c2].z; acc[a][c2] += d * d;
          d = pr[a].w - tg[c2].w; acc[a][c2] += d * d;
        }
    }
  }
  __syncthreads();   // staging reads done; alias predH region with 4x1024 partials
#pragma unroll
  for (int a = 0; a < 4; ++a)
#pragma unroll
    for (int c2 = 0; c2 < 4; ++c2)
      smem[w * 1024 + (ti & 3) + 4 * tj + 32 * a + 128 * c2 + 512 * (ti >> 2)] = acc[a][c2];
  __syncthreads();
  const int ti2 = tid >> 5, a2 = (tid >> 3) & 3, tj2 = tid & 7;
  float ov[4];
#pragma unroll
  for (int k = 0; k < 4; ++k) {
    int ad = (ti2 & 3) + 4 * tj2 + 32 * a2 + 128 * k + 512 * (ti2 >> 2);
    ov[k] = (smem[ad] + smem[ad + 1024]) + (smem[ad + 2048] + smem[ad + 3072]);
  }
  *reinterpret_cast<float4*>(cost_part + (size_t)bid * 1024 + tid * 4) =
      make_float4(ov[0], ov[1], ov[2], ov[3]);

  // ---- per-batch ticket: second arriver runs the hungarian tail ----
  volatile int* winflag = (int*)(smem + 1024);   // outside cs[0..1024)
  __threadfence();                               // release this block's plane
  if (tid == 0) {
    unsigned int t = atomicAdd(&bticket[b], 1u);
    *winflag = (t == 1u);
  }
  __syncthreads();                               // all 4 waves still alive
  if (!*winflag) return;                         // first arriver exits
  if (tid >= 64) return;                         // winner: only wave 0 continues
  __threadfence();                               // acquire the other plane

  const int lane = tid;
  float* cs = smem;                              // cost[32][32], aliases predH
  {
    const float4* c0p = reinterpret_cast<const float4*>(cost_part + (size_t)(2 * b) * 1024);
    const float4* c1p = reinterpret_cast<const float4*>(cost_part + (size_t)(2 * b + 1) * 1024);
    float4* cs4 = reinterpret_cast<float4*>(cs);
#pragma unroll
    for (int k = 0; k < 4; ++k) {
      int i = lane + 64 * k;
      float4 x = c0p[i], y = c1p[i];
      cs4[i] = make_float4(x.x + y.x, x.y + y.y, x.z + y.z, x.w + y.w);
    }
  }

  float lm = (lane < 32) ? lmask[b * 32 + lane] : 0.f;
  const int n = __popcll(__ballot(lm > 0.5f));
  float clfpart = 0.f;
  if (lane < 32 && lm > 0.5f) {
    int cc = clf[b * 32 + lane];
    clfpart = -logf(prob[(size_t)(b * 32 + lane) * 2 + cc]);
  }
  // single wave: drain LDS writes before reads (no __syncthreads after divergence)
  asm volatile("s_waitcnt lgkmcnt(0)" ::: "memory");

  const float FINF = 1e30f;
  const bool activecol = (lane < n);
  const int cl = lane & 31;   // lanes 32..63 mirror -> same-addr broadcast (free)

  // Reference-faithful broken JV (minv/way never persisted in the python):
  // each step: fresh argmin over free cols of cost[i0][j]-u[i0]-v[j];
  // "augment" collapses to p[j_final] = ri. The uniform u[i0] doesn't affect
  // the argmin, so the min runs on key = c - v; delta = min(key) - u[i0].
  float u_r = 0.f, v_j = 0.f;
  int p_j = -1;

  for (int ri = 0; ri < n; ++ri) {
    int i0 = ri;
    bool usedc = false;
    bool usedr = (lane == ri);
    float rowv = cs[i0 * 32 + cl];
    while (true) {
      float key = rowv - v_j;                   // reduced cost (sans uniform u0)
      bool act = activecol && !usedc;
      float m = act ? key : FINF;
      float u0 = readlane_f(u_r, i0);           // off the min critical path
      float mn = wave_min32_bcast(m);
      uint64_t tie = __ballot(m == mn);
      int j1 = __ffsll((unsigned long long)tie) - 1;  // numpy first-index tie-break
      int pj1 = readlane_i(p_j, j1);
      int i0n = pj1 < 0 ? 0 : pj1;
      float rowv_n = cs[i0n * 32 + cl];         // speculative next-row read (pre-branch)
      float delta = mn - u0;
      if (usedr) u_r += delta;                  // u[p[used]] += delta
      if (usedc) v_j -= delta;                  // v[used]    -= delta
      if (pj1 < 0) {                            // free column -> p[j1] = ri, done
        if (lane == j1) p_j = ri;
        break;
      }
      usedc = usedc || (lane == j1);
      i0 = pj1;
      usedr = usedr || (lane == i0);
      rowv = rowv_n;
    }
  }

  // column j matched to row p[j] -> contributes cost[p[j]][j]
  int pj = p_j < 0 ? 0 : p_j;
  float a = activecol ? cs[pj * 32 + cl] : 0.f;
#pragma unroll
  for (int off = 32; off; off >>= 1) {
    a += __shfl_xor(a, off);
    clfpart += __shfl_xor(clfpart, off);
  }
  if (lane == 0) {
    part[b * 3 + 0] = a;
    part[b * 3 + 1] = clfpart;
    part[b * 3 + 2] = (float)n;
  }

  // ---- global ticket: 512th hung completion runs finalize (R9 pattern) ----
  __threadfence();                       // release part[b]
  unsigned int t = 0;
  if (lane == 0) t = atomicAdd(gticket, 1u);
  t = (unsigned int)__shfl((int)t, 0);
  if (t == NB - 1u) {
    __threadfence();                     // acquire all part writes
    volatile const float* vp = part;
    double csum = 0.0, lsum = 0.0, nsum = 0.0;
    for (int i = lane; i < NB; i += 64) {
      csum += (double)vp[i * 3 + 0];
      lsum += (double)vp[i * 3 + 1];
      nsum += (double)vp[i * 3 + 2];
    }
#pragma unroll
    for (int off = 32; off; off >>= 1) {
      csum += __shfl_xor(csum, off);
      lsum += __shfl_xor(lsum, off);
      nsum += __shfl_xor(nsum, off);
    }
    if (lane == 0) {
      out[0] = (float)(csum / (nsum * 256.0));  // / sum(point_masks) = 256*sum(n)
      out[1] = (float)(lsum / nsum);            // / sum(line_masks)
    }
  }
}

extern "C" void kernel_launch(void* const* d_in, const int* in_sizes, int n_in,
                              void* d_out, int out_size, void* d_ws, size_t ws_size,
                              hipStream_t stream) {
  const float* pred = (const float*)d_in[0];   // [512,32,256,2] f32
  const float* prob = (const float*)d_in[1];   // [512,32,2] f32
  const float* tgt  = (const float*)d_in[2];   // [512,32,256,2] f32
  const float* lm   = (const float*)d_in[3];   // [512,32] f32
  const int*   clf  = (const int*)d_in[4];     // [512,32] i32

  float* cost_part = (float*)d_ws;                           // 1024*1024 f32 = 4 MB
  unsigned int* bticket = (unsigned int*)(cost_part + (size_t)1024 * 1024);  // [512]
  unsigned int* gticket = bticket + NB;                      // [1]
  float* part = (float*)(gticket + 1);                       // [512*3] f32

  // zero the 513 tickets (2052 B) - stream-ordered, graph-capturable (proven R9)
  hipMemsetAsync(bticket, 0, (NB + 1) * sizeof(unsigned int), stream);
  fused_kernel<<<NB * 2, 256, 0, stream>>>(pred, prob, tgt, lm, clf, cost_part,
                                           bticket, gticket, part, (float*)d_out);
}

// Round 14
// 60.008 us; speedup vs baseline: 3.3543x; 3.3543x over previous
//
#include <hip/hip_runtime.h>
#include <cstdint>
#include <cstddef>

#define NB 512
#define NL 32
#define KD 512     // P*D
#define KSLAB 128  // k-range per cost block (quarter-K)
#define PASS 128   // k per staging pass (single pass now)

// swizzled float-offset of chunk ch (4 floats) of row `row` in a [32][128] pass buffer.
__device__ __forceinline__ int swz128(int row, int ch) {
  int csw = (ch & ~15) | ((ch ^ (row >> 1)) & 15);
  return row * PASS + csw * 4;
}

// ---------------- cost kernel: 2048 blocks x 256 thr, quarter-K per block ----------------
// R10/R12/R13 lessons: (1) grid <= resident capacity => kernel wall = per-block
// serial latency; shrink per-block K to shrink the chain (R11->R12: halving K
// nearly halved cost wall). (2) launch_bounds arg2: VGPR cap = 256/arg2; arg2=2
// (cap 128) is the no-spill setting for this ~116-VGPR body. (3) NO fence/ticket
// fusion - R13's handoff cost 3.3x for unexplained latency reasons.
__global__ __launch_bounds__(256, 2)
void cost_kernel(const float* __restrict__ pred, const float* __restrict__ tgt,
                 float* __restrict__ cost_part) {
  __shared__ float smem[8192];   // 32 KB: predH[0..4096), tgtH[4096..8192); partials alias
  const int bid = blockIdx.x;
  const int b  = bid >> 2;
  const int ks = (bid & 3) * KSLAB;
  const int tid = threadIdx.x;
  float* predH = smem;
  float* tgtH  = smem + 4096;

  const int w = tid >> 6, l = tid & 63;   // 4 waves; wave w owns 8 of 32 row-chunks
  const int ti = l >> 3, tj = l & 7;      // 8x8 lanes of 4x4 output tiles
  float acc[4][4];
#pragma unroll
  for (int a = 0; a < 4; ++a)
#pragma unroll
    for (int c2 = 0; c2 < 4; ++c2) acc[a][c2] = 0.f;

  // single staging pass: [32][128] pred + tgt
  const size_t base = (size_t)b * (NL * KD) + ks;
#pragma unroll
  for (int it = 0; it < 4; ++it) {
    int chunk = tid + it * 256;          // 0..1023 -> row, chunk-in-row
    int row = chunk >> 5, ch = chunk & 31;
    const float4 pv = *reinterpret_cast<const float4*>(pred + base + (size_t)row * KD + ch * 4);
    const float4 tv = *reinterpret_cast<const float4*>(tgt  + base + (size_t)row * KD + ch * 4);
    int off = swz128(row, ch);
    *reinterpret_cast<float4*>(predH + off) = pv;
    *reinterpret_cast<float4*>(tgtH  + off) = tv;
  }
  __syncthreads();
#pragma unroll
  for (int c0 = 0; c0 < 8; ++c0) {
    const int c = (w << 3) + c0;         // wave's 8 chunks
    float4 pr[4], tg[4];
#pragma unroll
    for (int r = 0; r < 4; ++r) {
      pr[r] = *reinterpret_cast<const float4*>(predH + swz128(4 * ti + r, c));
      tg[r] = *reinterpret_cast<const float4*>(tgtH  + swz128(4 * tj + r, c));
    }
#pragma unroll
    for (int a = 0; a < 4; ++a)
#pragma unroll
      for (int c2 = 0; c2 < 4; ++c2) {
        float d;
        d = pr[a].x - tg[c2].x; acc[a][c2] += d * d;
        d = pr[a].y - tg[c2].y; acc[a][c2] += d * d;
        d = pr[a].z - tg[c2].z; acc[a][c2] += d * d;
        d = pr[a].w - tg[c2].w; acc[a][c2] += d * d;
      }
  }
  __syncthreads();   // staging reads done; alias predH region with 4x1024 partials
  // disjoint bit-field layout: bank = (ti&3)+4*tj -> 2-way max (free)
#pragma unroll
  for (int a = 0; a < 4; ++a)
#pragma unroll
    for (int c2 = 0; c2 < 4; ++c2)
      smem[w * 1024 + (ti & 3) + 4 * tj + 32 * a + 128 * c2 + 512 * (ti >> 2)] = acc[a][c2];
  __syncthreads();
  const int ti2 = tid >> 5, a2 = (tid >> 3) & 3, tj2 = tid & 7;
  float ov[4];
#pragma unroll
  for (int k = 0; k < 4; ++k) {
    int ad = (ti2 & 3) + 4 * tj2 + 32 * a2 + 128 * k + 512 * (ti2 >> 2);
    ov[k] = (smem[ad] + smem[ad + 1024]) + (smem[ad + 2048] + smem[ad + 3072]);
  }
  *reinterpret_cast<float4*>(cost_part + (size_t)bid * 1024 + tid * 4) =
      make_float4(ov[0], ov[1], ov[2], ov[3]);
}

// ---------------- hungarian kernel: 512 blocks x 64 thr (R7-proven body) ----------------
__device__ __forceinline__ float readlane_f(float x, int lane) {
  return __int_as_float(__builtin_amdgcn_readlane(__float_as_int(x), lane));
}
__device__ __forceinline__ int readlane_i(int x, int lane) {
  return __builtin_amdgcn_readlane(x, lane);
}

template<int CTRL, int RM>
__device__ __forceinline__ float dppmin(float x) {
  int m = __builtin_amdgcn_update_dpp(__float_as_int(x), __float_as_int(x), CTRL, RM, 0xf, false);
  return fminf(x, __int_as_float(m));
}
// min over lanes 0..31, broadcast to all lanes via SGPR
__device__ __forceinline__ float wave_min32_bcast(float x) {
  x = dppmin<0xB1, 0xf>(x);   // quad_perm xor1
  x = dppmin<0x4E, 0xf>(x);   // quad_perm xor2
  x = dppmin<0x124, 0xf>(x);  // row_ror:4
  x = dppmin<0x128, 0xf>(x);  // row_ror:8 -> row16 min everywhere
  x = dppmin<0x142, 0xa>(x);  // row_bcast:15 -> lanes 16..31 = min(lanes 0..31)
  return readlane_f(x, 31);
}

__global__ __launch_bounds__(64)
void hung_kernel(const float* __restrict__ cost_part,
                 const float* __restrict__ prob,
                 const float* __restrict__ lmask,
                 const int* __restrict__ clf,
                 float* __restrict__ part) {
  __shared__ float cs[1024];    // cost[32][32]: row-select = 1 conflict-free ds_read_b32
  const int b = blockIdx.x;
  const int lane = threadIdx.x;

  // stage cost = sum of the batch's four K-slab partial planes
  {
    const float4* p0 = reinterpret_cast<const float4*>(cost_part + (size_t)(4 * b + 0) * 1024);
    const float4* p1 = reinterpret_cast<const float4*>(cost_part + (size_t)(4 * b + 1) * 1024);
    const float4* p2 = reinterpret_cast<const float4*>(cost_part + (size_t)(4 * b + 2) * 1024);
    const float4* p3 = reinterpret_cast<const float4*>(cost_part + (size_t)(4 * b + 3) * 1024);
    float4* cs4 = reinterpret_cast<float4*>(cs);
#pragma unroll
    for (int k = 0; k < 4; ++k) {
      int i = lane + 64 * k;
      float4 x0 = p0[i], x1 = p1[i], x2 = p2[i], x3 = p3[i];
      cs4[i] = make_float4((x0.x + x1.x) + (x2.x + x3.x),
                           (x0.y + x1.y) + (x2.y + x3.y),
                           (x0.z + x1.z) + (x2.z + x3.z),
                           (x0.w + x1.w) + (x2.w + x3.w));
    }
  }

  float lm = (lane < 32) ? lmask[b * 32 + lane] : 0.f;
  const int n = __popcll(__ballot(lm > 0.5f));
  float clfpart = 0.f;
  if (lane < 32 && lm > 0.5f) {
    int cc = clf[b * 32 + lane];
    clfpart = -logf(prob[(size_t)(b * 32 + lane) * 2 + cc]);
  }
  __syncthreads();   // cs visible

  const float FINF = 1e30f;
  const bool activecol = (lane < n);
  const int cl = lane & 31;   // lanes 32..63 mirror -> same-addr broadcast (free)

  // Reference-faithful broken JV (minv/way never persisted in the python):
  // each step: fresh argmin over free cols of cost[i0][j]-u[i0]-v[j];
  // "augment" collapses to p[j_final] = ri. The uniform u[i0] doesn't affect
  // the argmin, so the min runs on key = c - v; delta = min(key) - u[i0].
  float u_r = 0.f, v_j = 0.f;
  int p_j = -1;

  for (int ri = 0; ri < n; ++ri) {
    int i0 = ri;
    bool usedc = false;
    bool usedr = (lane == ri);
    float rowv = cs[i0 * 32 + cl];
    while (true) {
      float key = rowv - v_j;                   // reduced cost (sans uniform u0)
      bool act = activecol && !usedc;
      float m = act ? key : FINF;
      float u0 = readlane_f(u_r, i0);           // off the min critical path
      float mn = wave_min32_bcast(m);
      uint64_t tie = __ballot(m == mn);
      int j1 = __ffsll((unsigned long long)tie) - 1;  // numpy first-index tie-break
      int pj1 = readlane_i(p_j, j1);
      int i0n = pj1 < 0 ? 0 : pj1;
      float rowv_n = cs[i0n * 32 + cl];         // speculative next-row read (pre-branch)
      float delta = mn - u0;
      if (usedr) u_r += delta;                  // u[p[used]] += delta
      if (usedc) v_j -= delta;                  // v[used]    -= delta
      if (pj1 < 0) {                            // free column -> p[j1] = ri, done
        if (lane == j1) p_j = ri;
        break;
      }
      usedc = usedc || (lane == j1);
      i0 = pj1;
      usedr = usedr || (lane == i0);
      rowv = rowv_n;
    }
  }

  // column j matched to row p[j] -> contributes cost[p[j]][j]
  int pj = p_j < 0 ? 0 : p_j;
  float a = activecol ? cs[pj * 32 + cl] : 0.f;
#pragma unroll
  for (int off = 32; off; off >>= 1) {
    a += __shfl_xor(a, off);
    clfpart += __shfl_xor(clfpart, off);
  }
  if (lane == 0) {
    part[b * 3 + 0] = a;
    part[b * 3 + 1] = clfpart;
    part[b * 3 + 2] = (float)n;
  }
}

// ---------------- finalize ----------------
__global__ void finalize_kernel(const float* __restrict__ part, float* __restrict__ out) {
  const int lane = threadIdx.x;   // 64 threads, 1 block: deterministic fixed-order reduce
  double cs = 0.0, ls = 0.0, ns = 0.0;
  for (int i = lane; i < NB; i += 64) {
    cs += (double)part[i * 3 + 0];
    ls += (double)part[i * 3 + 1];
    ns += (double)part[i * 3 + 2];
  }
#pragma unroll
  for (int off = 32; off; off >>= 1) {
    cs += __shfl_xor(cs, off);
    ls += __shfl_xor(ls, off);
    ns += __shfl_xor(ns, off);
  }
  if (lane == 0) {
    out[0] = (float)(cs / (ns * 256.0));  // / sum(point_masks) = 256 * sum(n)
    out[1] = (float)(ls / ns);            // / sum(line_masks)
  }
}

extern "C" void kernel_launch(void* const* d_in, const int* in_sizes, int n_in,
                              void* d_out, int out_size, void* d_ws, size_t ws_size,
                              hipStream_t stream) {
  const float* pred = (const float*)d_in[0];   // [512,32,256,2] f32
  const float* prob = (const float*)d_in[1];   // [512,32,2] f32
  const float* tgt  = (const float*)d_in[2];   // [512,32,256,2] f32
  const float* lm   = (const float*)d_in[3];   // [512,32] f32
  const int*   clf  = (const int*)d_in[4];     // [512,32] i32

  float* cost_part = (float*)d_ws;                       // 2048*1024 f32 = 8 MB
  float* part = cost_part + (size_t)2048 * 1024;         // 512*3 f32

  cost_kernel<<<NB * 4, 256, 0, stream>>>(pred, tgt, cost_part);
  hung_kernel<<<NB, 64, 0, stream>>>(cost_part, prob, lm, clf, part);
  finalize_kernel<<<1, 64, 0, stream>>>(part, (float*)d_out);
}

// Round 15
// 59.366 us; speedup vs baseline: 3.3905x; 1.0108x over previous
//
#include <hip/hip_runtime.h>
#include <cstdint>
#include <cstddef>

#define NB 512
#define NL 32
#define KD 512     // P*D
#define KSLAB 128  // k-range per cost block (quarter-K)
#define PASS 128   // k per staging pass (single pass)

// swizzled float-offset of chunk ch (4 floats) of row `row` in a [32][128] pass buffer.
__device__ __forceinline__ int swz128(int row, int ch) {
  int csw = (ch & ~15) | ((ch ^ (row >> 1)) & 15);
  return row * PASS + csw * 4;
}

// ---------------- cost kernel: 2048 blocks x 256 thr (R14-proven; unchanged) ----------------
__global__ __launch_bounds__(256, 2)
void cost_kernel(const float* __restrict__ pred, const float* __restrict__ tgt,
                 float* __restrict__ cost_part) {
  __shared__ float smem[8192];   // 32 KB: predH[0..4096), tgtH[4096..8192); partials alias
  const int bid = blockIdx.x;
  const int b  = bid >> 2;
  const int ks = (bid & 3) * KSLAB;
  const int tid = threadIdx.x;
  float* predH = smem;
  float* tgtH  = smem + 4096;

  const int w = tid >> 6, l = tid & 63;
  const int ti = l >> 3, tj = l & 7;
  float acc[4][4];
#pragma unroll
  for (int a = 0; a < 4; ++a)
#pragma unroll
    for (int c2 = 0; c2 < 4; ++c2) acc[a][c2] = 0.f;

  const size_t base = (size_t)b * (NL * KD) + ks;
#pragma unroll
  for (int it = 0; it < 4; ++it) {
    int chunk = tid + it * 256;
    int row = chunk >> 5, ch = chunk & 31;
    const float4 pv = *reinterpret_cast<const float4*>(pred + base + (size_t)row * KD + ch * 4);
    const float4 tv = *reinterpret_cast<const float4*>(tgt  + base + (size_t)row * KD + ch * 4);
    int off = swz128(row, ch);
    *reinterpret_cast<float4*>(predH + off) = pv;
    *reinterpret_cast<float4*>(tgtH  + off) = tv;
  }
  __syncthreads();
#pragma unroll
  for (int c0 = 0; c0 < 8; ++c0) {
    const int c = (w << 3) + c0;
    float4 pr[4], tg[4];
#pragma unroll
    for (int r = 0; r < 4; ++r) {
      pr[r] = *reinterpret_cast<const float4*>(predH + swz128(4 * ti + r, c));
      tg[r] = *reinterpret_cast<const float4*>(tgtH  + swz128(4 * tj + r, c));
    }
#pragma unroll
    for (int a = 0; a < 4; ++a)
#pragma unroll
      for (int c2 = 0; c2 < 4; ++c2) {
        float d;
        d = pr[a].x - tg[c2].x; acc[a][c2] += d * d;
        d = pr[a].y - tg[c2].y; acc[a][c2] += d * d;
        d = pr[a].z - tg[c2].z; acc[a][c2] += d * d;
        d = pr[a].w - tg[c2].w; acc[a][c2] += d * d;
      }
  }
  __syncthreads();
#pragma unroll
  for (int a = 0; a < 4; ++a)
#pragma unroll
    for (int c2 = 0; c2 < 4; ++c2)
      smem[w * 1024 + (ti & 3) + 4 * tj + 32 * a + 128 * c2 + 512 * (ti >> 2)] = acc[a][c2];
  __syncthreads();
  const int ti2 = tid >> 5, a2 = (tid >> 3) & 3, tj2 = tid & 7;
  float ov[4];
#pragma unroll
  for (int k = 0; k < 4; ++k) {
    int ad = (ti2 & 3) + 4 * tj2 + 32 * a2 + 128 * k + 512 * (ti2 >> 2);
    ov[k] = (smem[ad] + smem[ad + 1024]) + (smem[ad + 2048] + smem[ad + 3072]);
  }
  *reinterpret_cast<float4*>(cost_part + (size_t)bid * 1024 + tid * 4) =
      make_float4(ov[0], ov[1], ov[2], ov[3]);
}

// ---------------- hungarian kernel: 512 blocks x 64 thr ----------------
__device__ __forceinline__ float readlane_f(float x, int lane) {
  return __int_as_float(__builtin_amdgcn_readlane(__float_as_int(x), lane));
}
__device__ __forceinline__ int readlane_i(int x, int lane) {
  return __builtin_amdgcn_readlane(x, lane);
}

template<int CTRL, int RM>
__device__ __forceinline__ unsigned int dppumin(unsigned int x) {
  unsigned int m = (unsigned int)__builtin_amdgcn_update_dpp((int)x, (int)x, CTRL, RM, 0xf, false);
  return x < m ? x : m;   // v_min_u32
}
// u32 min over lanes 0..31, returned as wave-uniform scalar
__device__ __forceinline__ unsigned int wave_umin32_bcast(unsigned int x) {
  x = dppumin<0xB1, 0xf>(x);   // quad_perm xor1
  x = dppumin<0x4E, 0xf>(x);   // quad_perm xor2
  x = dppumin<0x124, 0xf>(x);  // row_ror:4
  x = dppumin<0x128, 0xf>(x);  // row_ror:8 -> row16 min everywhere
  x = dppumin<0x142, 0xa>(x);  // row_bcast:15 -> lanes 16..31 = min(lanes 0..31)
  return (unsigned int)__builtin_amdgcn_readlane((int)x, 31);
}

__global__ __launch_bounds__(64)
void hung_kernel(const float* __restrict__ cost_part,
                 const float* __restrict__ prob,
                 const float* __restrict__ lmask,
                 const int* __restrict__ clf,
                 float* __restrict__ part) {
  __shared__ float cs[1024];    // cost[32][32]: row-select = 1 conflict-free ds_read_b32
  const int b = blockIdx.x;
  const int lane = threadIdx.x;

  // stage cost = sum of the batch's four K-slab partial planes
  {
    const float4* p0 = reinterpret_cast<const float4*>(cost_part + (size_t)(4 * b + 0) * 1024);
    const float4* p1 = reinterpret_cast<const float4*>(cost_part + (size_t)(4 * b + 1) * 1024);
    const float4* p2 = reinterpret_cast<const float4*>(cost_part + (size_t)(4 * b + 2) * 1024);
    const float4* p3 = reinterpret_cast<const float4*>(cost_part + (size_t)(4 * b + 3) * 1024);
    float4* cs4 = reinterpret_cast<float4*>(cs);
#pragma unroll
    for (int k = 0; k < 4; ++k) {
      int i = lane + 64 * k;
      float4 x0 = p0[i], x1 = p1[i], x2 = p2[i], x3 = p3[i];
      cs4[i] = make_float4((x0.x + x1.x) + (x2.x + x3.x),
                           (x0.y + x1.y) + (x2.y + x3.y),
                           (x0.z + x1.z) + (x2.z + x3.z),
                           (x0.w + x1.w) + (x2.w + x3.w));
    }
  }

  float lm = (lane < 32) ? lmask[b * 32 + lane] : 0.f;
  const int n = __popcll(__ballot(lm > 0.5f));
  float clfpart = 0.f;
  if (lane < 32 && lm > 0.5f) {
    int cc = clf[b * 32 + lane];
    clfpart = -logf(prob[(size_t)(b * 32 + lane) * 2 + cc]);
  }
  __syncthreads();   // cs visible

  const float FINF = 1e30f;
  const bool activecol = (lane < n);
  const int cl = lane & 31;   // lanes 32..63 mirror -> same-addr broadcast (free)

  // Reference-faithful broken JV (minv/way never persisted in the python):
  // each step: fresh argmin over free cols of cost[i0][j]-u[i0]-v[j];
  // "augment" collapses to p[j_final] = ri. Uniform u[i0] doesn't affect the
  // argmin -> min over key = c - v; delta = min(key) - u[i0].
  // Argmin via PACKED sortable-u32: 5 LSBs replaced by lane index, single
  // v_min_u32 DPP cascade yields min AND first-index argmin in one scalar
  // (removes ballot + ffsll + extra readlane from the loop-carried chain).
  // Ties within 1..31 ulp may flip vs numpy (loss shift ~1e-7 << 7.8e-2 thr).
  float u_r = 0.f, v_j = 0.f;
  int p_j = -1;

  for (int ri = 0; ri < n; ++ri) {
    int i0 = ri;
    bool usedc = false;
    bool usedr = (lane == ri);
    float rowv = cs[i0 * 32 + cl];
    float u0 = readlane_f(u_r, i0);
    while (true) {
      float key = rowv - v_j;                   // reduced cost (sans uniform u0)
      bool act = activecol && !usedc;
      float m = act ? key : FINF;
      unsigned int mu = __float_as_uint(m);
      mu ^= (unsigned int)((int)mu >> 31) | 0x80000000u;   // monotone f32->u32
      unsigned int packed = (mu & 0xFFFFFFE0u) | (unsigned int)cl;
      unsigned int pmin = wave_umin32_bcast(packed);
      int j1 = (int)(pmin & 31u);               // first-min column
      float mnv = readlane_f(m, j1);            // exact min value
      int pj1 = readlane_i(p_j, j1);
      float delta = mnv - u0;
      if (usedr) u_r += delta;                  // u[p[used]] += delta
      if (usedc) v_j -= delta;                  // v[used]    -= delta
      if (pj1 < 0) {                            // free column -> p[j1] = ri, done
        if (lane == j1) p_j = ri;
        break;
      }
      usedc = usedc || (lane == j1);
      usedr = usedr || (lane == pj1);
      i0 = pj1;
      rowv = cs[i0 * 32 + cl];
      u0 = readlane_f(u_r, i0);                 // post-update u[i0]
    }
  }

  // column j matched to row p[j] -> contributes cost[p[j]][j]
  int pj = p_j < 0 ? 0 : p_j;
  float a = activecol ? cs[pj * 32 + cl] : 0.f;
#pragma unroll
  for (int off = 32; off; off >>= 1) {
    a += __shfl_xor(a, off);
    clfpart += __shfl_xor(clfpart, off);
  }
  if (lane == 0) {
    part[b * 3 + 0] = a;
    part[b * 3 + 1] = clfpart;
    part[b * 3 + 2] = (float)n;
  }
}

// ---------------- finalize ----------------
__global__ void finalize_kernel(const float* __restrict__ part, float* __restrict__ out) {
  const int lane = threadIdx.x;   // 64 threads, 1 block: deterministic fixed-order reduce
  double cs = 0.0, ls = 0.0, ns = 0.0;
  for (int i = lane; i < NB; i += 64) {
    cs += (double)part[i * 3 + 0];
    ls += (double)part[i * 3 + 1];
    ns += (double)part[i * 3 + 2];
  }
#pragma unroll
  for (int off = 32; off; off >>= 1) {
    cs += __shfl_xor(cs, off);
    ls += __shfl_xor(ls, off);
    ns += __shfl_xor(ns, off);
  }
  if (lane == 0) {
    out[0] = (float)(cs / (ns * 256.0));  // / sum(point_masks) = 256 * sum(n)
    out[1] = (float)(ls / ns);            // / sum(line_masks)
  }
}

extern "C" void kernel_launch(void* const* d_in, const int* in_sizes, int n_in,
                              void* d_out, int out_size, void* d_ws, size_t ws_size,
                              hipStream_t stream) {
  const float* pred = (const float*)d_in[0];   // [512,32,256,2] f32
  const float* prob = (const float*)d_in[1];   // [512,32,2] f32
  const float* tgt  = (const float*)d_in[2];   // [512,32,256,2] f32
  const float* lm   = (const float*)d_in[3];   // [512,32] f32
  const int*   clf  = (const int*)d_in[4];     // [512,32] i32

  float* cost_part = (float*)d_ws;                       // 2048*1024 f32 = 8 MB
  float* part = cost_part + (size_t)2048 * 1024;         // 512*3 f32

  cost_kernel<<<NB * 4, 256, 0, stream>>>(pred, tgt, cost_part);
  hung_kernel<<<NB, 64, 0, stream>>>(cost_part, prob, lm, clf, part);
  finalize_kernel<<<1, 64, 0, stream>>>(part, (float*)d_out);
}